// Round 1
// baseline (138.712 us; speedup 1.0000x reference)
//
#include <hip/hip_runtime.h>
#include <math.h>

// Problem constants (from reference):
//   B=8, R=50 (rafs has 2R=100 channels), C=150, H=W=128, N=4096, K=192
#define KPTS   192
#define RDIM   50
#define HDIM   128
#define WDIM   128
#define NREL   4096
#define CDIM   150
#define LOSS_W 0.1f
#define WPB    4          // waves (relations) per block
#define BLK    (WPB * 64)
#define PLANE  (HDIM * WDIM)

// Stage 1: one wave per relation. Lane l covers samples k = l, l+64, l+128.
// BRANCHLESS sample loop: all 6 scattered gathers are issued back-to-back
// (addresses for k >= num are clamped to the num-1 sample, which lands on
// already-fetched cachelines of the same line), then a masked accumulate
// consumes them. This collapses the previous 2-3 serial exec-masked gather
// rounds (s_cbranch_execz between chunks) into ONE memory-latency round.
// Dup check uses __shfl_up to fetch lane l-1's bitwise-exact px/py instead
// of recomputing with a second fp32 division.
__global__ __launch_bounds__(BLK) void relation_partial_kernel(
    const float* __restrict__ rafs,      // (B, 2R, H, W)
    const float* __restrict__ heatmaps,  // (B, C, H, W)
    const int*   __restrict__ rels,      // (N, 8)
    float* __restrict__ ws)              // (N,) per-relation logp
{
    const int wave = threadIdx.x >> 6;
    const int lane = threadIdx.x & 63;
    const int rel  = blockIdx.x * WPB + wave;

    // Two 16B loads instead of eight 4B loads; then broadcast to SGPRs.
    const int4* r4 = (const int4*)(rels + (size_t)rel * 8);
    const int4 ra = r4[0];   // bi, scls, sy, sx
    const int4 rb = r4[1];   // ocls, oy, ox, pred
    const int bi   = __builtin_amdgcn_readfirstlane(ra.x);
    const int scls = __builtin_amdgcn_readfirstlane(ra.y);
    const int sy   = __builtin_amdgcn_readfirstlane(ra.z);
    const int sx   = __builtin_amdgcn_readfirstlane(ra.w);
    const int ocls = __builtin_amdgcn_readfirstlane(rb.x);
    const int oy   = __builtin_amdgcn_readfirstlane(rb.y);
    const int ox   = __builtin_amdgcn_readfirstlane(rb.z);
    const int pred = __builtin_amdgcn_readfirstlane(rb.w);

    // Scalar-address loads; latency overlaps the whole sample pipeline.
    const float subj = heatmaps[(((size_t)bi * CDIM + (size_t)scls) * HDIM + (size_t)sy) * WDIM + (size_t)sx];
    const float obj  = heatmaps[(((size_t)bi * CDIM + (size_t)ocls) * HDIM + (size_t)oy) * WDIM + (size_t)ox];

    const float dx = (float)(ox - sx);
    const float dy = (float)(oy - sy);
    const float norms = sqrtf(dx * dx + dy * dy);
    const float ux = dx / norms;
    const float uy = dy / norms;
    const int   num = (int)ceilf(norms);           // 1..180 < 192
    const float denom = (float)((num - 1) > 1 ? (num - 1) : 1);

    const float oxf = (float)ox, oyf = (float)oy;
    const float sxmox = (float)(sx - ox);
    const float symoy = (float)(sy - oy);

    const size_t rafbase =
        ((size_t)bi * (2 * RDIM) + (size_t)(2 * pred)) * (size_t)PLANE;

    // ---- Phase 1: compute all sample points, issue ALL gathers (no branches)
    int   pxs[3], pys[3];
    float vxs[3], vys[3];

    #pragma unroll
    for (int s = 0; s < 3; ++s) {
        const int k  = lane + 64 * s;
        const int kk = (k < num) ? k : (num - 1);       // clamp: safe addr, same line
        const float t  = (float)kk / denom;             // EXACT reference expression
        const int   px = (int)rintf(oxf + t * sxmox);
        const int   py = (int)rintf(oyf + t * symoy);
        pxs[s] = px;
        pys[s] = py;
        const size_t off = (size_t)py * WDIM + (size_t)px;
        vxs[s] = rafs[rafbase + off];
        vys[s] = rafs[rafbase + (size_t)PLANE + off];
    }

    // ---- Phase 2: masked accumulate. Previous sample's px/py comes from the
    // neighboring lane (bitwise identical to recomputation).
    float dot  = 0.0f;
    int   vcnt = 0;
    int   px63 = -1, py63 = -1;      // sentinel: k=0 is never a dup

    #pragma unroll
    for (int s = 0; s < 3; ++s) {
        int pxp = __shfl_up(pxs[s], 1, 64);
        int pyp = __shfl_up(pys[s], 1, 64);
        if (lane == 0) { pxp = px63; pyp = py63; }      // chunk-boundary stitch
        px63 = __shfl(pxs[s], 63, 64);
        py63 = __shfl(pys[s], 63, 64);

        const int  k   = lane + 64 * s;
        const bool dup = (pxs[s] == pxp) && (pys[s] == pyp);
        if ((k < num) && !dup) {
            float vx = fminf(fmaxf(vxs[s], -1.0f), 1.0f);
            float vy = fminf(fmaxf(vys[s], -1.0f), 1.0f);
            dot  += vx * ux + vy * uy;
            vcnt += 1;
        }
    }

    // Wave64 shuffle reduction.
    #pragma unroll
    for (int off = 32; off > 0; off >>= 1) {
        dot  += __shfl_down(dot,  off, 64);
        vcnt += __shfl_down(vcnt, off, 64);
    }

    if (lane == 0) {
        float integral = dot / (float)vcnt;          // vcnt >= 1 (k=0 always valid)
        integral = fminf(fmaxf(integral, 0.0f), 1.0f);
        const float rs = subj * obj * integral;
        ws[rel] = logf(fmaxf(rs, 1e-12f));
    }
}

// Stage 2: deterministic sum of NREL partials -> scalar loss. One block.
// (Unchanged — verified bit-exact, absmax=0.)
__global__ __launch_bounds__(256) void reduce_kernel(
    const float* __restrict__ part,   // (NREL,)
    float* __restrict__ out)
{
    const int tid = threadIdx.x;
    float acc = 0.0f;
    #pragma unroll
    for (int j = 0; j < NREL / 256; ++j)
        acc += part[tid + j * 256];

    #pragma unroll
    for (int off = 32; off > 0; off >>= 1)
        acc += __shfl_down(acc, off, 64);

    __shared__ float s[4];
    const int wave = tid >> 6;
    const int lane = tid & 63;
    if (lane == 0) s[wave] = acc;
    __syncthreads();
    if (tid == 0) {
        const float total = s[0] + s[1] + s[2] + s[3];
        out[0] = total * (-LOSS_W / (float)NREL);
    }
}

extern "C" void kernel_launch(void* const* d_in, const int* in_sizes, int n_in,
                              void* d_out, int out_size, void* d_ws, size_t ws_size,
                              hipStream_t stream) {
    const float* rafs     = (const float*)d_in[0];
    const float* heatmaps = (const float*)d_in[1];
    const int*   rels     = (const int*)d_in[2];
    float*       out      = (float*)d_out;
    float*       part     = (float*)d_ws;

    relation_partial_kernel<<<NREL / WPB, BLK, 0, stream>>>(rafs, heatmaps, rels, part);
    reduce_kernel<<<1, 256, 0, stream>>>(part, out);
}